// Round 9
// baseline (1041.213 us; speedup 1.0000x reference)
//
#include <hip/hip_runtime.h>
#include <stdint.h>

#define CIN 256
#define COUT 128
#define BATCH 8
#define HH 64
#define WW 64
#define XROW 66

// xb2: padded bf16 input, [B][66 rows][66 cols][4 cb][8 slot][8 ch], slot pre-swizzled by (col&7)
#define XB2_BYTES ((size_t)BATCH * XROW * XROW * CIN * 2)
// gw3: fused weights, [9 taps][2 py][4 cb][256 row=co*2+px][8 slot][8 ch], slot pre-swizzled by (row&7)
#define GW3_BYTES ((size_t)9 * 2 * 4 * 256 * 64 * 2)

typedef __bf16 bf16x8 __attribute__((ext_vector_type(8)));
typedef float f32x4 __attribute__((ext_vector_type(4)));

__device__ __forceinline__ unsigned short f2bf(float f) {
  unsigned int u = __float_as_uint(f);
  u += 0x7fffu + ((u >> 16) & 1u);
  return (unsigned short)(u >> 16);
}

__device__ __forceinline__ void gload_lds16(const void* g, void* l) {
  __builtin_amdgcn_global_load_lds(
      (__attribute__((address_space(1))) void*)(uintptr_t)g,
      (__attribute__((address_space(3))) void*)l, 16, 0, 0);
}

// ---------------- prep: zero the xb2 border (replaces full memset) ----------------
__global__ __launch_bounds__(256) void prep_border(unsigned short* __restrict__ xb2) {
  int u = blockIdx.x * 256 + threadIdx.x;
  if (u >= 66560) return;
  int b = u / 8320, v = u - b * 8320;
  int row, col, cs;
  if (v < 4224) {
    int rr = v / 2112;
    int rem = v - rr * 2112;
    row = rr * 65; col = rem >> 5; cs = rem & 31;
  } else {
    int v2 = v - 4224;
    row = 1 + (v2 >> 6);
    int rem = v2 & 63;
    col = (rem >> 5) * 65; cs = rem & 31;
  }
  size_t o = (((size_t)(b * XROW + row) * XROW + col) * 32 + cs) * 8;
  *reinterpret_cast<uint4*>(&xb2[o]) = make_uint4(0, 0, 0, 0);
}

// ---------------- prep: x -> padded channel-last swizzled bf16 ----------------
__global__ __launch_bounds__(256) void prep_x(const float* __restrict__ x,
                                              unsigned short* __restrict__ xb2) {
  int b = blockIdx.x >> 6, iy = blockIdx.x & 63;
  __shared__ __align__(16) unsigned short lds[64][264];  // [ix][c]
  int t = threadIdx.x;
  int cq = t >> 6, ix = t & 63;
  for (int ci = 0; ci < 64; ++ci) {
    int c = ci * 4 + cq;
    float v = x[(((size_t)b * CIN + c) * HH + iy) * WW + ix];
    lds[ix][c] = f2bf(v);
  }
  __syncthreads();
  for (int it = 0; it < 8; ++it) {
    int u = it * 256 + t;  // 2048 units of 16B: 64 ix * 32 (cb,slot)
    int ixo = u >> 5;
    int q = u & 31, cb = q >> 3, slot = q & 7;
    int col = ixo + 1;  // padded col
    int c0 = cb * 64 + 8 * (slot ^ (col & 7));
    uint4 val = *reinterpret_cast<const uint4*>(&lds[ixo][c0]);
    size_t o = ((((size_t)(b * XROW + (iy + 1)) * XROW + col) * 4 + cb) * 8 + slot) * 8;
    *reinterpret_cast<uint4*>(&xb2[o]) = val;
  }
}

// ---------------- prep: fuse He-scale * conv3x3 (x) FIR into per-parity 3x3 taps ----------------
__global__ __launch_bounds__(256) void prep_w(const float* __restrict__ w,
                                              const float* __restrict__ f,
                                              unsigned short* __restrict__ gw3) {
  __shared__ float fs[16];
  int co = blockIdx.x;
  int c = threadIdx.x;
  if (c < 16) fs[c] = f[c];
  __syncthreads();
  float wl[3][3];
  const float he = 1.0f / 48.0f;  // 1/sqrt(256*9)
#pragma unroll
  for (int dy = 0; dy < 3; ++dy)
#pragma unroll
    for (int dx = 0; dx < 3; ++dx)
      wl[dy][dx] = w[((size_t)(co * CIN + c) * 3 + dy) * 3 + dx] * he;
  int cb = c >> 6, cl = c & 63;
  int ce = cl & 7;
  for (int d = 0; d < 3; ++d)
    for (int e = 0; e < 3; ++e)
      for (int py = 0; py < 2; ++py)
        for (int px = 0; px < 2; ++px) {
          int ty = 2 * d + 1 - py, tx = 2 * e + 1 - px;  // taps of 6x6 composite g
          float acc = 0.f;
          for (int dy = 0; dy < 3; ++dy) {
            int a = ty - dy;
            if (a < 0 || a > 3) continue;
            for (int dx = 0; dx < 3; ++dx) {
              int bb = tx - dx;
              if (bb < 0 || bb > 3) continue;
              acc += wl[dy][dx] * fs[a * 4 + bb];
            }
          }
          int row = co * 2 + px;
          int slot = (cl >> 3) ^ (row & 7);
          size_t o = ((((size_t)(d * 3 + e) * 2 + py) * 4 + cb) * 256 + row) * 64 + slot * 8 + ce;
          gw3[o] = f2bf(acc);
        }
}

// ---------------- main: implicit-GEMM polyphase conv ----------------
// BM=256 (rows co*2+px), BN=128 (2 output sub-rows x 64 cols), 8 waves 4M x 2N,
// wave tile 64x64, 16x16x32 MFMA. Grid 512 = 2 blocks/CU, free-running (syncthreads
// only at the 4 cb boundaries). SOFTWARE PIPELINE: af (weights, global/L2) for step
// s+1 issued at top of step s (~620cy MFMA cover >= L2 latency); bv(k8=1) ds_reads
// before MFMA(k8=0); bv(k8=0) of s+1 before MFMA(k8=1). 2-step unroll, static regs.
__global__ __launch_bounds__(512, 4) void conv_main(
    const unsigned short* __restrict__ xb2,
    const unsigned short* __restrict__ gw3,
    const float* __restrict__ bias,
    float* __restrict__ out) {
  __shared__ __align__(16) unsigned char xs[2][33792];  // [buf][4 xrow][66 col][8 slot][16B]

  const int bid = blockIdx.x;
  const int b = bid & 7;          // XCD b-affinity: xb2 slice L2-resident
  const int py = (bid >> 3) & 1;
  const int m0 = (bid >> 4) * 2;  // 2 output sub-rows per block

  const int t = threadIdx.x;
  const int lane = t & 63;
  const int wave = t >> 6;
  const int wmi = wave >> 1;  // 0..3: M quarter (64 rows)
  const int wn = wave & 1;    // 0..1: output sub-row
  const int l15 = lane & 15, l4 = lane >> 4;

  f32x4 acc[4][4] = {};
  bf16x8 afA[4], afB[4], afC[4], afD[4];  // cur k0, cur k1, next k0, next k1
  bf16x8 bvA[4], bvB[4];                  // cur k0, cur k1

  const char* xbase = (const char*)xb2 + (size_t)((b * XROW + m0) * (XROW * 32)) * 16;
  const char* gw3b = (const char*)gw3;

  const int afoff0 = (wmi * 64 + l15) * 128 + ((l4 ^ (l15 & 7)) << 4);  // k8=0
  const int afoff1 = afoff0 ^ 64;                                       // k8=1

#define STAGE_X(BB, CB)                                                         \
  do {                                                                          \
    for (int it = 0; it < 5; ++it) {                                            \
      int u = it * 512 + t;                                                     \
      if (u < 2112) {                                                           \
        int rr = u / 528;                                                       \
        int rem = u - rr * 528;                                                 \
        int col = rem >> 3, slot = rem & 7;                                     \
        size_t go = (size_t)(rr * XROW + col) * 32 + (CB)*8 + slot;             \
        gload_lds16(xbase + go * 16, (unsigned char*)xs[BB] + (size_t)u * 16);  \
      }                                                                         \
    }                                                                           \
  } while (0)

  // read 4 bv fragments for (buf, d_, e_, k8)
#define READ_BV(DST, BUF, D_, E_, K8)                                                  \
  do {                                                                                 \
    const int colb_ = l15 + (E_);                                                      \
    const unsigned char* xr_ = &xs[BUF][(wn + (D_)) * 8448 + colb_ * 128 +             \
                                        ((((K8)*4 + l4) ^ (colb_ & 7)) << 4)];         \
    _Pragma("unroll") for (int j = 0; j < 4; ++j)                                      \
        (DST)[j] = *(const bf16x8*)(xr_ + j * 2048);                                   \
  } while (0)

#define LOAD_AF(DST, GP, OFF)                                                          \
  do {                                                                                 \
    _Pragma("unroll") for (int i = 0; i < 4; ++i)                                      \
        (DST)[i] = *(const bf16x8*)((GP) + (OFF) + i * 2048);                          \
  } while (0)

#define CLUSTER(AF, BV)                                                                  \
  do {                                                                                   \
    __builtin_amdgcn_s_setprio(1);                                                       \
    _Pragma("unroll") for (int i = 0; i < 4; ++i)                                        \
      _Pragma("unroll") for (int j = 0; j < 4; ++j)                                      \
          acc[i][j] =                                                                    \
              __builtin_amdgcn_mfma_f32_16x16x32_bf16((AF)[i], (BV)[j], acc[i][j], 0, 0, 0); \
    __builtin_amdgcn_s_setprio(0);                                                       \
  } while (0)

  // one step: consume AF0/AF1 (+bvA/bvB), prefetch next-step af into NF0/NF1
#define STEP(AF0, AF1, NF0, NF1)                                                  \
  do {                                                                            \
    int nde = de + 1, ncb = cb, nd = d, ne = e + 1;                               \
    if (ne == 3) { ne = 0; ++nd; }                                                \
    if (nde == 9) { nde = 0; ++ncb; nd = 0; ne = 0; }                             \
    const int ccb = (ncb > 3) ? 3 : ncb;                                          \
    const char* gnxt = gw3b + ((((size_t)nde * 2 + py) * 4 + ccb) << 15);         \
    LOAD_AF(NF0, gnxt, afoff0);                                                   \
    LOAD_AF(NF1, gnxt, afoff1);                                                   \
    if (de == 1 && cb < 3) STAGE_X((cb & 1) ^ 1, cb + 1);                         \
    READ_BV(bvB, cb & 1, d, e, 1);                                                \
    CLUSTER(AF0, bvA);                                                            \
    if (de != 8) {                                                                \
      READ_BV(bvA, cb & 1, nd, ne, 0);  /* next-step k0, hides under cluster2 */  \
      CLUSTER(AF1, bvB);                                                          \
    } else {                                                                      \
      CLUSTER(AF1, bvB);                                                          \
      __syncthreads();                   /* cb boundary fence */                  \
      READ_BV(bvA, ncb & 1, nd, ne, 0);                                           \
    }                                                                             \
    d = nd; e = ne; de = nde; cb = ncb;                                           \
  } while (0)

  // prologue: X(cb=0), af step-0 halves; fence; then bv k0 of step 0
  STAGE_X(0, 0);
  {
    const char* g0 = gw3b + (((size_t)py * 4) << 15);
    LOAD_AF(afA, g0, afoff0);
    LOAD_AF(afB, g0, afoff1);
  }
  __syncthreads();
  int d = 0, e = 0, de = 0, cb = 0;
  READ_BV(bvA, 0, 0, 0, 0);

  for (int sp = 0; sp < 18; ++sp) {
    STEP(afA, afB, afC, afD);
    STEP(afC, afD, afA, afB);
  }
#undef STAGE_X
#undef READ_BV
#undef LOAD_AF
#undef CLUSTER
#undef STEP

  const float kSqrt2 = 1.41421356237309515f;
  const int oh = 2 * (m0 + wn) + py;
#pragma unroll
  for (int i = 0; i < 4; ++i) {
    const int row0 = wmi * 64 + i * 16 + l4 * 4;  // even
    const int co0 = row0 >> 1;                    // r=0,1 -> co0 (px=0,1); r=2,3 -> co0+1
    const float bs0 = bias[co0], bs1 = bias[co0 + 1];
#pragma unroll
    for (int j = 0; j < 4; ++j) {
      const int n = j * 16 + l15;
      float v[4];
#pragma unroll
      for (int r = 0; r < 4; ++r) {
        float vv = acc[i][j][r] + ((r < 2) ? bs0 : bs1);
        vv = (vv < 0.f ? 0.01f * vv : vv) * kSqrt2;
        v[r] = fminf(fmaxf(vv, -256.f), 265.f);
      }
      float2* p0 = (float2*)&out[(((size_t)b * COUT + co0) * 128 + oh) * 128 + 2 * n];
      float2* p1 = (float2*)&out[(((size_t)b * COUT + co0 + 1) * 128 + oh) * 128 + 2 * n];
      *p0 = make_float2(v[0], v[1]);
      *p1 = make_float2(v[2], v[3]);
    }
  }
}

extern "C" void kernel_launch(void* const* d_in, const int* in_sizes, int n_in,
                              void* d_out, int out_size, void* d_ws, size_t ws_size,
                              hipStream_t stream) {
  const float* x = (const float*)d_in[0];
  const float* w = (const float*)d_in[1];
  const float* bias = (const float*)d_in[2];
  const float* f = (const float*)d_in[3];
  float* out = (float*)d_out;

  unsigned short* xb2 = (unsigned short*)d_ws;
  unsigned short* gw3 = (unsigned short*)((char*)d_ws + XB2_BYTES);

  hipLaunchKernelGGL(prep_border, dim3(260), dim3(256), 0, stream, xb2);
  hipLaunchKernelGGL(prep_x, dim3(BATCH * HH), dim3(256), 0, stream, x, xb2);
  hipLaunchKernelGGL(prep_w, dim3(128), dim3(256), 0, stream, w, f, gw3);
  hipLaunchKernelGGL(conv_main, dim3(512), dim3(512), 0, stream, xb2, gw3, bias, out);
}

// Round 10
// 95.531 us; speedup vs baseline: 10.8992x; 10.8992x over previous
//
#include <hip/hip_runtime.h>
#include <stdint.h>

#define CIN 256
#define COUT 128
#define BATCH 8
#define HH 64
#define WW 64
#define XROW 66

// xb2: padded bf16 input, [B][66 rows][66 cols][4 cb][8 slot][8 ch], slot pre-swizzled by (col&7)
#define XB2_BYTES ((size_t)BATCH * XROW * XROW * CIN * 2)
// gw3: fused weights, [9 taps][2 py][4 cb][256 row=co*2+px][8 slot][8 ch], slot pre-swizzled by (row&7)
#define GW3_BYTES ((size_t)9 * 2 * 4 * 256 * 64 * 2)

typedef __bf16 bf16x8 __attribute__((ext_vector_type(8)));
typedef float f32x4 __attribute__((ext_vector_type(4)));

__device__ __forceinline__ unsigned short f2bf(float f) {
  unsigned int u = __float_as_uint(f);
  u += 0x7fffu + ((u >> 16) & 1u);
  return (unsigned short)(u >> 16);
}

__device__ __forceinline__ void gload_lds16(const void* g, void* l) {
  __builtin_amdgcn_global_load_lds(
      (__attribute__((address_space(1))) void*)(uintptr_t)g,
      (__attribute__((address_space(3))) void*)l, 16, 0, 0);
}

// ---------------- prep: zero the xb2 border (replaces full memset) ----------------
__global__ __launch_bounds__(256) void prep_border(unsigned short* __restrict__ xb2) {
  int u = blockIdx.x * 256 + threadIdx.x;
  if (u >= 66560) return;
  int b = u / 8320, v = u - b * 8320;
  int row, col, cs;
  if (v < 4224) {
    int rr = v / 2112;
    int rem = v - rr * 2112;
    row = rr * 65; col = rem >> 5; cs = rem & 31;
  } else {
    int v2 = v - 4224;
    row = 1 + (v2 >> 6);
    int rem = v2 & 63;
    col = (rem >> 5) * 65; cs = rem & 31;
  }
  size_t o = (((size_t)(b * XROW + row) * XROW + col) * 32 + cs) * 8;
  *reinterpret_cast<uint4*>(&xb2[o]) = make_uint4(0, 0, 0, 0);
}

// ---------------- prep: x -> padded channel-last swizzled bf16 ----------------
__global__ __launch_bounds__(256) void prep_x(const float* __restrict__ x,
                                              unsigned short* __restrict__ xb2) {
  int b = blockIdx.x >> 6, iy = blockIdx.x & 63;
  __shared__ __align__(16) unsigned short lds[64][264];  // [ix][c]
  int t = threadIdx.x;
  int cq = t >> 6, ix = t & 63;
  for (int ci = 0; ci < 64; ++ci) {
    int c = ci * 4 + cq;
    float v = x[(((size_t)b * CIN + c) * HH + iy) * WW + ix];
    lds[ix][c] = f2bf(v);
  }
  __syncthreads();
  for (int it = 0; it < 8; ++it) {
    int u = it * 256 + t;  // 2048 units of 16B: 64 ix * 32 (cb,slot)
    int ixo = u >> 5;
    int q = u & 31, cb = q >> 3, slot = q & 7;
    int col = ixo + 1;  // padded col
    int c0 = cb * 64 + 8 * (slot ^ (col & 7));
    uint4 val = *reinterpret_cast<const uint4*>(&lds[ixo][c0]);
    size_t o = ((((size_t)(b * XROW + (iy + 1)) * XROW + col) * 4 + cb) * 8 + slot) * 8;
    *reinterpret_cast<uint4*>(&xb2[o]) = val;
  }
}

// ---------------- prep: fuse He-scale * conv3x3 (x) FIR into per-parity 3x3 taps ----------------
__global__ __launch_bounds__(256) void prep_w(const float* __restrict__ w,
                                              const float* __restrict__ f,
                                              unsigned short* __restrict__ gw3) {
  __shared__ float fs[16];
  int co = blockIdx.x;
  int c = threadIdx.x;
  if (c < 16) fs[c] = f[c];
  __syncthreads();
  float wl[3][3];
  const float he = 1.0f / 48.0f;  // 1/sqrt(256*9)
#pragma unroll
  for (int dy = 0; dy < 3; ++dy)
#pragma unroll
    for (int dx = 0; dx < 3; ++dx)
      wl[dy][dx] = w[((size_t)(co * CIN + c) * 3 + dy) * 3 + dx] * he;
  int cb = c >> 6, cl = c & 63;
  int ce = cl & 7;
  for (int d = 0; d < 3; ++d)
    for (int e = 0; e < 3; ++e)
      for (int py = 0; py < 2; ++py)
        for (int px = 0; px < 2; ++px) {
          int ty = 2 * d + 1 - py, tx = 2 * e + 1 - px;  // taps of 6x6 composite g
          float acc = 0.f;
          for (int dy = 0; dy < 3; ++dy) {
            int a = ty - dy;
            if (a < 0 || a > 3) continue;
            for (int dx = 0; dx < 3; ++dx) {
              int bb = tx - dx;
              if (bb < 0 || bb > 3) continue;
              acc += wl[dy][dx] * fs[a * 4 + bb];
            }
          }
          int row = co * 2 + px;
          int slot = (cl >> 3) ^ (row & 7);
          size_t o = ((((size_t)(d * 3 + e) * 2 + py) * 4 + cb) * 256 + row) * 64 + slot * 8 + ce;
          gw3[o] = f2bf(acc);
        }
}

// ---------------- main: implicit-GEMM polyphase conv ----------------
// BM=256 (rows co*2+px), BN=128 (2 output sub-rows x 64 cols), 8 waves 4M x 2N,
// wave tile 64x64, 16x16x32 MFMA. launch_bounds(512,2): VGPR cap 256 -> NO SPILL
// (round-9's (512,4) cap of 128 spilled ~60 regs to scratch: WRITE_SIZE 3.4GB).
// Free-running (syncthreads only at the 4 cb boundaries). Software pipeline:
// af (weights, L2) for step s+1 issued at top of step s (~620cy MFMA cover);
// bv(k8=1) ds_reads before MFMA(k8=0); bv(k8=0) of s+1 before MFMA(k8=1).
__global__ __launch_bounds__(512, 2) void conv_main(
    const unsigned short* __restrict__ xb2,
    const unsigned short* __restrict__ gw3,
    const float* __restrict__ bias,
    float* __restrict__ out) {
  __shared__ __align__(16) unsigned char xs[2][33792];  // [buf][4 xrow][66 col][8 slot][16B]

  const int bid = blockIdx.x;
  const int b = bid & 7;          // XCD b-affinity: xb2 slice L2-resident
  const int py = (bid >> 3) & 1;
  const int m0 = (bid >> 4) * 2;  // 2 output sub-rows per block

  const int t = threadIdx.x;
  const int lane = t & 63;
  const int wave = t >> 6;
  const int wmi = wave >> 1;  // 0..3: M quarter (64 rows)
  const int wn = wave & 1;    // 0..1: output sub-row
  const int l15 = lane & 15, l4 = lane >> 4;

  f32x4 acc[4][4] = {};
  bf16x8 afA[4], afB[4], afC[4], afD[4];  // cur k0, cur k1, next k0, next k1
  bf16x8 bvA[4], bvB[4];                  // cur k0, cur k1

  const char* xbase = (const char*)xb2 + (size_t)((b * XROW + m0) * (XROW * 32)) * 16;
  const char* gw3b = (const char*)gw3;

  const int afoff0 = (wmi * 64 + l15) * 128 + ((l4 ^ (l15 & 7)) << 4);  // k8=0
  const int afoff1 = afoff0 ^ 64;                                       // k8=1

#define STAGE_X(BB, CB)                                                         \
  do {                                                                          \
    for (int it = 0; it < 5; ++it) {                                            \
      int u = it * 512 + t;                                                     \
      if (u < 2112) {                                                           \
        int rr = u / 528;                                                       \
        int rem = u - rr * 528;                                                 \
        int col = rem >> 3, slot = rem & 7;                                     \
        size_t go = (size_t)(rr * XROW + col) * 32 + (CB)*8 + slot;             \
        gload_lds16(xbase + go * 16, (unsigned char*)xs[BB] + (size_t)u * 16);  \
      }                                                                         \
    }                                                                           \
  } while (0)

  // read 4 bv fragments for (buf, d_, e_, k8)
#define READ_BV(DST, BUF, D_, E_, K8)                                                  \
  do {                                                                                 \
    const int colb_ = l15 + (E_);                                                      \
    const unsigned char* xr_ = &xs[BUF][(wn + (D_)) * 8448 + colb_ * 128 +             \
                                        ((((K8)*4 + l4) ^ (colb_ & 7)) << 4)];         \
    _Pragma("unroll") for (int j = 0; j < 4; ++j)                                      \
        (DST)[j] = *(const bf16x8*)(xr_ + j * 2048);                                   \
  } while (0)

#define LOAD_AF(DST, GP, OFF)                                                          \
  do {                                                                                 \
    _Pragma("unroll") for (int i = 0; i < 4; ++i)                                      \
        (DST)[i] = *(const bf16x8*)((GP) + (OFF) + i * 2048);                          \
  } while (0)

#define CLUSTER(AF, BV)                                                                  \
  do {                                                                                   \
    __builtin_amdgcn_s_setprio(1);                                                       \
    _Pragma("unroll") for (int i = 0; i < 4; ++i)                                        \
      _Pragma("unroll") for (int j = 0; j < 4; ++j)                                      \
          acc[i][j] =                                                                    \
              __builtin_amdgcn_mfma_f32_16x16x32_bf16((AF)[i], (BV)[j], acc[i][j], 0, 0, 0); \
    __builtin_amdgcn_s_setprio(0);                                                       \
  } while (0)

  // one step: consume AF0/AF1 (+bvA/bvB), prefetch next-step af into NF0/NF1
#define STEP(AF0, AF1, NF0, NF1)                                                  \
  do {                                                                            \
    int nde = de + 1, ncb = cb, nd = d, ne = e + 1;                               \
    if (ne == 3) { ne = 0; ++nd; }                                                \
    if (nde == 9) { nde = 0; ++ncb; nd = 0; ne = 0; }                             \
    const int ccb = (ncb > 3) ? 3 : ncb;                                          \
    const char* gnxt = gw3b + ((((size_t)nde * 2 + py) * 4 + ccb) << 15);         \
    LOAD_AF(NF0, gnxt, afoff0);                                                   \
    LOAD_AF(NF1, gnxt, afoff1);                                                   \
    if (de == 1 && cb < 3) STAGE_X((cb & 1) ^ 1, cb + 1);                         \
    READ_BV(bvB, cb & 1, d, e, 1);                                                \
    CLUSTER(AF0, bvA);                                                            \
    if (de != 8) {                                                                \
      READ_BV(bvA, cb & 1, nd, ne, 0);  /* next-step k0, hides under cluster2 */  \
      CLUSTER(AF1, bvB);                                                          \
    } else {                                                                      \
      CLUSTER(AF1, bvB);                                                          \
      __syncthreads();                   /* cb boundary fence */                  \
      READ_BV(bvA, ncb & 1, nd, ne, 0);                                           \
    }                                                                             \
    d = nd; e = ne; de = nde; cb = ncb;                                           \
  } while (0)

  // prologue: X(cb=0), af step-0 halves; fence; then bv k0 of step 0
  STAGE_X(0, 0);
  {
    const char* g0 = gw3b + (((size_t)py * 4) << 15);
    LOAD_AF(afA, g0, afoff0);
    LOAD_AF(afB, g0, afoff1);
  }
  __syncthreads();
  int d = 0, e = 0, de = 0, cb = 0;
  READ_BV(bvA, 0, 0, 0, 0);

  for (int sp = 0; sp < 18; ++sp) {
    STEP(afA, afB, afC, afD);
    STEP(afC, afD, afA, afB);
  }
#undef STAGE_X
#undef READ_BV
#undef LOAD_AF
#undef CLUSTER
#undef STEP

  const float kSqrt2 = 1.41421356237309515f;
  const int oh = 2 * (m0 + wn) + py;
#pragma unroll
  for (int i = 0; i < 4; ++i) {
    const int row0 = wmi * 64 + i * 16 + l4 * 4;  // even
    const int co0 = row0 >> 1;                    // r=0,1 -> co0 (px=0,1); r=2,3 -> co0+1
    const float bs0 = bias[co0], bs1 = bias[co0 + 1];
#pragma unroll
    for (int j = 0; j < 4; ++j) {
      const int n = j * 16 + l15;
      float v[4];
#pragma unroll
      for (int r = 0; r < 4; ++r) {
        float vv = acc[i][j][r] + ((r < 2) ? bs0 : bs1);
        vv = (vv < 0.f ? 0.01f * vv : vv) * kSqrt2;
        v[r] = fminf(fmaxf(vv, -256.f), 265.f);
      }
      float2* p0 = (float2*)&out[(((size_t)b * COUT + co0) * 128 + oh) * 128 + 2 * n];
      float2* p1 = (float2*)&out[(((size_t)b * COUT + co0 + 1) * 128 + oh) * 128 + 2 * n];
      *p0 = make_float2(v[0], v[1]);
      *p1 = make_float2(v[2], v[3]);
    }
  }
}

extern "C" void kernel_launch(void* const* d_in, const int* in_sizes, int n_in,
                              void* d_out, int out_size, void* d_ws, size_t ws_size,
                              hipStream_t stream) {
  const float* x = (const float*)d_in[0];
  const float* w = (const float*)d_in[1];
  const float* bias = (const float*)d_in[2];
  const float* f = (const float*)d_in[3];
  float* out = (float*)d_out;

  unsigned short* xb2 = (unsigned short*)d_ws;
  unsigned short* gw3 = (unsigned short*)((char*)d_ws + XB2_BYTES);

  hipLaunchKernelGGL(prep_border, dim3(260), dim3(256), 0, stream, xb2);
  hipLaunchKernelGGL(prep_x, dim3(BATCH * HH), dim3(256), 0, stream, x, xb2);
  hipLaunchKernelGGL(prep_w, dim3(128), dim3(256), 0, stream, w, f, gw3);
  hipLaunchKernelGGL(conv_main, dim3(512), dim3(512), 0, stream, xb2, gw3, bias, out);
}

// Round 11
// 82.215 us; speedup vs baseline: 12.6646x; 1.1620x over previous
//
#include <hip/hip_runtime.h>
#include <stdint.h>

#define CIN 256
#define COUT 128
#define BATCH 8
#define HH 64
#define WW 64
#define XROW 66

// xb2: padded bf16 input, [B][66 rows][66 cols][4 cb][8 slot][8 ch], slot pre-swizzled by (col&7)
#define XB2_BYTES ((size_t)BATCH * XROW * XROW * CIN * 2)
// gw3: fused weights, [9 taps][2 py][4 cb][256 row=co*2+px][8 slot][8 ch], slot pre-swizzled by (row&7)
#define GW3_BYTES ((size_t)9 * 2 * 4 * 256 * 64 * 2)

typedef __bf16 bf16x8 __attribute__((ext_vector_type(8)));
typedef float f32x4 __attribute__((ext_vector_type(4)));

__device__ __forceinline__ unsigned short f2bf(float f) {
  unsigned int u = __float_as_uint(f);
  u += 0x7fffu + ((u >> 16) & 1u);
  return (unsigned short)(u >> 16);
}

__device__ __forceinline__ void gload_lds16(const void* g, void* l) {
  __builtin_amdgcn_global_load_lds(
      (__attribute__((address_space(1))) void*)(uintptr_t)g,
      (__attribute__((address_space(3))) void*)l, 16, 0, 0);
}

// ---------------- fused prep: prep_x (512 blk) + prep_w (128 blk) + border (260 blk) ----------------
// All three stages are independent (disjoint writes); one launch replaces
// memset + prep_border + prep_x + prep_w (saves 3 launch gaps + 17.8MB memset).
__global__ __launch_bounds__(256) void prep_all(const float* __restrict__ x,
                                                const float* __restrict__ w,
                                                const float* __restrict__ f,
                                                unsigned short* __restrict__ xb2,
                                                unsigned short* __restrict__ gw3) {
  __shared__ __align__(16) unsigned short lds[64][264];  // prep_x staging; fs aliases it
  const int blk = blockIdx.x;
  const int t = threadIdx.x;

  if (blk < 512) {
    // ---- prep_x: x -> padded channel-last swizzled bf16 (interior) ----
    int b = blk >> 6, iy = blk & 63;
    int cq = t >> 6, ix = t & 63;
    for (int ci = 0; ci < 64; ++ci) {
      int c = ci * 4 + cq;
      float v = x[(((size_t)b * CIN + c) * HH + iy) * WW + ix];
      lds[ix][c] = f2bf(v);
    }
    __syncthreads();
    for (int it = 0; it < 8; ++it) {
      int u = it * 256 + t;  // 2048 units of 16B: 64 ix * 32 (cb,slot)
      int ixo = u >> 5;
      int q = u & 31, cb = q >> 3, slot = q & 7;
      int col = ixo + 1;  // padded col
      int c0 = cb * 64 + 8 * (slot ^ (col & 7));
      uint4 val = *reinterpret_cast<const uint4*>(&lds[ixo][c0]);
      size_t o = ((((size_t)(b * XROW + (iy + 1)) * XROW + col) * 4 + cb) * 8 + slot) * 8;
      *reinterpret_cast<uint4*>(&xb2[o]) = val;
    }
  } else if (blk < 640) {
    // ---- prep_w: fuse He-scale * conv3x3 (x) FIR into per-parity 3x3 taps ----
    float* fs = (float*)lds;
    int co = blk - 512;
    int c = t;
    if (c < 16) fs[c] = f[c];
    __syncthreads();
    float wl[3][3];
    const float he = 1.0f / 48.0f;  // 1/sqrt(256*9)
#pragma unroll
    for (int dy = 0; dy < 3; ++dy)
#pragma unroll
      for (int dx = 0; dx < 3; ++dx)
        wl[dy][dx] = w[((size_t)(co * CIN + c) * 3 + dy) * 3 + dx] * he;
    int cb = c >> 6, cl = c & 63;
    int ce = cl & 7;
    for (int d = 0; d < 3; ++d)
      for (int e = 0; e < 3; ++e)
        for (int py = 0; py < 2; ++py)
          for (int px = 0; px < 2; ++px) {
            int ty = 2 * d + 1 - py, tx = 2 * e + 1 - px;  // taps of 6x6 composite g
            float acc = 0.f;
            for (int dy = 0; dy < 3; ++dy) {
              int a = ty - dy;
              if (a < 0 || a > 3) continue;
              for (int dx = 0; dx < 3; ++dx) {
                int bb = tx - dx;
                if (bb < 0 || bb > 3) continue;
                acc += wl[dy][dx] * fs[a * 4 + bb];
              }
            }
            int row = co * 2 + px;
            int slot = (cl >> 3) ^ (row & 7);
            size_t o =
                ((((size_t)(d * 3 + e) * 2 + py) * 4 + cb) * 256 + row) * 64 + slot * 8 + ce;
            gw3[o] = f2bf(acc);
          }
  } else {
    // ---- border zeroing: rows {0,65} all cols + cols {0,65} rows 1..64 ----
    int u = (blk - 640) * 256 + t;
    if (u >= 66560) return;
    int b = u / 8320, v = u - b * 8320;
    int row, col, cs;
    if (v < 4224) {
      int rr = v / 2112;
      int rem = v - rr * 2112;
      row = rr * 65; col = rem >> 5; cs = rem & 31;
    } else {
      int v2 = v - 4224;
      row = 1 + (v2 >> 6);
      int rem = v2 & 63;
      col = (rem >> 5) * 65; cs = rem & 31;
    }
    size_t o = (((size_t)(b * XROW + row) * XROW + col) * 32 + cs) * 8;
    *reinterpret_cast<uint4*>(&xb2[o]) = make_uint4(0, 0, 0, 0);
  }
}

// ---------------- main: implicit-GEMM polyphase conv, 256x256 tile, 8 waves ----------------
// (Best-measured variant: round-4 K-major 2-phase, conv 79.2-80.8 us.)
// M=256 (row = co*2+px), N=256 spatial (4 out sub-rows x 64 cols; wave wn owns sub-row wn),
// K=2304 in 36 steps of 64. Per phase: {2x global_load_lds (A half, next step) |
// 12 ds_read_b128 (af[8]+bv[4]) -> bar -> lgkm(0) -> setprio(1) -> 32 MFMA -> setprio(0)};
// A prefetched 1 step ahead, drained by vmcnt(0) at step end.
__global__ __launch_bounds__(512, 2) void conv_main(
    const unsigned short* __restrict__ xb2,
    const unsigned short* __restrict__ gw3,
    const float* __restrict__ bias,
    float* __restrict__ out) {
  __shared__ __align__(16) unsigned char smem[65536 + 51200];
  unsigned short* at0 = (unsigned short*)smem;            // A buf 0: [256 row][8 slot][8 ch]
  unsigned short* at1 = (unsigned short*)(smem + 32768);  // A buf 1
  unsigned short* xt = (unsigned short*)(smem + 65536);   // X: [6 xrow][66 col][8 slot][8 ch]

  const int bid = blockIdx.x;
  const int py = bid >> 7;       // 0..1
  const int r0 = bid & 127;
  const int b = r0 >> 4;
  const int m0 = (r0 & 15) * 4;  // 4 output sub-rows per block

  const int t = threadIdx.x;
  const int lane = t & 63;
  const int wave = t >> 6;
  const int wm = wave >> 2;  // 0..1: M half
  const int wn = wave & 3;   // 0..3: output sub-row
  const int l15 = lane & 15, l4 = lane >> 4;

  f32x4 acc[8][4] = {};

  const char* xbase = (const char*)xb2 + (size_t)((b * XROW + m0) * (XROW * 32)) * 16;

#define STAGE_A_HALF(buf, de_, cb_, H)                                                \
  do {                                                                                \
    const char* g = (const char*)gw3 + ((((size_t)(de_)*2 + py) * 4 + (cb_)) << 15) + \
                    (H)*16384;                                                        \
    int off = (H)*16384 + t * 16;                                                     \
    gload_lds16(g + t * 16, (char*)(buf) + off);                                      \
    gload_lds16(g + t * 16 + 8192, (char*)(buf) + off + 8192);                        \
  } while (0)

#define STAGE_X(cb_)                                                          \
  do {                                                                        \
    for (int it = 0; it < 7; ++it) {                                          \
      int u = it * 512 + t;                                                   \
      if (u < 3200) {                                                         \
        int us = (u < 3168) ? u : (u - 64);                                   \
        int rr = us / 528;                                                    \
        int rem = us - rr * 528;                                              \
        int col = rem >> 3, slot = rem & 7;                                   \
        size_t go = (size_t)(rr * XROW + col) * 32 + (cb_)*8 + slot;          \
        gload_lds16(xbase + go * 16, (char*)xt + (size_t)u * 16);             \
      }                                                                       \
    }                                                                         \
  } while (0)

#define BAR()                        \
  do {                               \
    asm volatile("" ::: "memory");   \
    __builtin_amdgcn_s_barrier();    \
    asm volatile("" ::: "memory");   \
  } while (0)

#define KPHASE(K8, XSTMT)                                                                 \
  do {                                                                                    \
    bf16x8 af[8], bfv[4];                                                                 \
    _Pragma("unroll") for (int i = 0; i < 8; ++i) {                                       \
      int row = wm * 128 + i * 16 + l15;                                                  \
      int slot = ((K8)*4 + l4) ^ (row & 7);                                               \
      af[i] = *(const bf16x8*)(A + (size_t)row * 64 + slot * 8);                          \
    }                                                                                     \
    _Pragma("unroll") for (int j = 0; j < 4; ++j) {                                       \
      int col = j * 16 + l15 + e;                                                         \
      int slot = ((K8)*4 + l4) ^ (col & 7);                                               \
      bfv[j] = *(const bf16x8*)(xt + ((size_t)xr * 66 + col) * 64 + slot * 8);            \
    }                                                                                     \
    BAR();                                                                                \
    XSTMT;                                                                                \
    asm volatile("s_waitcnt lgkmcnt(0)" ::: "memory");                                    \
    __builtin_amdgcn_sched_barrier(0);                                                    \
    __builtin_amdgcn_s_setprio(1);                                                        \
    _Pragma("unroll") for (int i = 0; i < 8; ++i)                                         \
      _Pragma("unroll") for (int j = 0; j < 4; ++j)                                       \
        acc[i][j] =                                                                       \
            __builtin_amdgcn_mfma_f32_16x16x32_bf16(af[i], bfv[j], acc[i][j], 0, 0, 0);   \
    __builtin_amdgcn_s_setprio(0);                                                        \
    __builtin_amdgcn_sched_barrier(0);                                                    \
  } while (0)

  // prologue: first A tile + first X tile
  STAGE_A_HALF(at0, 0, 0, 0);
  STAGE_A_HALF(at0, 0, 0, 1);
  STAGE_X(0);
  asm volatile("s_waitcnt vmcnt(0)" ::: "memory");
  BAR();

  unsigned short* A = at0;
  unsigned short* An = at1;
  int cb = 0, de = 0, d = 0, e = 0;
  for (int s = 0; s < 36; ++s) {
    const int xr = wn + d;
    const int notlast = (s < 35);
    const int nde = (de == 8) ? 0 : de + 1;
    const int ncb = (de == 8) ? cb + 1 : cb;

    if (notlast) STAGE_A_HALF(An, nde, ncb, 0);
    KPHASE(0, {});
    BAR();
    if (notlast) STAGE_A_HALF(An, nde, ncb, 1);
    KPHASE(1, {
      if (de == 8 && cb < 3) STAGE_X(cb + 1);  // xt reads done at this phase's barrier
    });
    asm volatile("s_waitcnt vmcnt(0)" ::: "memory");  // next A (+X at boundary) complete
    BAR();

    { unsigned short* tmp = A; A = An; An = tmp; }
    ++e;
    if (e == 3) { e = 0; ++d; }
    ++de;
    if (de == 9) { de = 0; d = 0; e = 0; ++cb; }
  }
#undef STAGE_A_HALF
#undef STAGE_X
#undef KPHASE

  const float kSqrt2 = 1.41421356237309515f;
  const int oh = 2 * (m0 + wn) + py;
#pragma unroll
  for (int i = 0; i < 8; ++i) {
    const int row0 = wm * 128 + i * 16 + l4 * 4;  // even
    const int co0 = row0 >> 1;                    // r=0,1 -> co0 (px=0,1); r=2,3 -> co0+1
    const float bs0 = bias[co0], bs1 = bias[co0 + 1];
#pragma unroll
    for (int j = 0; j < 4; ++j) {
      const int n = j * 16 + l15;
      float v[4];
#pragma unroll
      for (int r = 0; r < 4; ++r) {
        float vv = acc[i][j][r] + ((r < 2) ? bs0 : bs1);
        vv = (vv < 0.f ? 0.01f * vv : vv) * kSqrt2;
        v[r] = fminf(fmaxf(vv, -256.f), 265.f);
      }
      float2* p0 = (float2*)&out[(((size_t)b * COUT + co0) * 128 + oh) * 128 + 2 * n];
      float2* p1 = (float2*)&out[(((size_t)b * COUT + co0 + 1) * 128 + oh) * 128 + 2 * n];
      *p0 = make_float2(v[0], v[1]);
      *p1 = make_float2(v[2], v[3]);
    }
  }
}

extern "C" void kernel_launch(void* const* d_in, const int* in_sizes, int n_in,
                              void* d_out, int out_size, void* d_ws, size_t ws_size,
                              hipStream_t stream) {
  const float* x = (const float*)d_in[0];
  const float* w = (const float*)d_in[1];
  const float* bias = (const float*)d_in[2];
  const float* f = (const float*)d_in[3];
  float* out = (float*)d_out;

  unsigned short* xb2 = (unsigned short*)d_ws;
  unsigned short* gw3 = (unsigned short*)((char*)d_ws + XB2_BYTES);

  hipLaunchKernelGGL(prep_all, dim3(900), dim3(256), 0, stream, x, w, f, xb2, gw3);
  hipLaunchKernelGGL(conv_main, dim3(256), dim3(512), 0, stream, xb2, gw3, bias, out);
}